// Round 13
// baseline (178.260 us; speedup 1.0000x reference)
//
#include <hip/hip_runtime.h>
#include <hip/hip_bf16.h>

#define DMODEL 512
#define LEN 2048
#define NBATCH 4
#define TOPK 7          // k = int(log(2048)) = 7
#define LDK 40          // padded LDS stride (bf16 elems): 80B rows keep 16B alignment

typedef __attribute__((ext_vector_type(8))) short short8;
typedef __attribute__((ext_vector_type(4))) float floatx4;

__device__ __forceinline__ float b2f(ushort h) {
  union { uint u; float f; } c; c.u = ((uint)h) << 16; return c.f;
}
__device__ __forceinline__ ushort f2b(float f) {
  union { float f; uint u; } c; c.f = f;
  uint u = c.u;
  uint r = (u + 0x7fffu + ((u >> 16) & 1u)) >> 16;   // RNE
  return (ushort)r;
}

__device__ __forceinline__ float ld1(const void* p, size_t i, int bf) {
  return bf ? b2f(((const ushort*)p)[i]) : ((const float*)p)[i];
}
__device__ __forceinline__ void ld4v(const void* p, size_t i, int bf, float* o) {
  if (bf) {
    uint2 v = *(const uint2*)((const ushort*)p + i);
    const ushort* s = (const ushort*)&v;
#pragma unroll
    for (int j = 0; j < 4; ++j) o[j] = b2f(s[j]);
  } else {
    float4 a = *(const float4*)((const float*)p + i);
    o[0] = a.x; o[1] = a.y; o[2] = a.z; o[3] = a.w;
  }
}
__device__ __forceinline__ void ld8v(const void* p, size_t i, int bf, float* o) {
  if (bf) {
    uint4 v = *(const uint4*)((const ushort*)p + i);
    const ushort* s = (const ushort*)&v;
#pragma unroll
    for (int j = 0; j < 8; ++j) o[j] = b2f(s[j]);
  } else {
    float4 a = *(const float4*)((const float*)p + i);
    float4 b = *(const float4*)((const float*)p + i + 4);
    o[0] = a.x; o[1] = a.y; o[2] = a.z; o[3] = a.w;
    o[4] = b.x; o[5] = b.y; o[6] = b.z; o[7] = b.w;
  }
}

// CK-style LDS barrier that does NOT drain vmcnt — keeps global loads in flight.
__device__ __forceinline__ void block_sync_lds() {
  asm volatile("s_waitcnt lgkmcnt(0)" ::: "memory");
  __builtin_amdgcn_s_barrier();
}

// per-block dtype self-detect from wq's first 512 words (L2-hot after first use).
__device__ __forceinline__ int detect_bf16(const void* probe) {
  __shared__ int s_flag;
  int t = threadIdx.x;
  if (t < 64) {
    const uint4* p = (const uint4*)probe;
    uint4 a = p[t * 2];
    uint4 b = p[t * 2 + 1];
    uint w[8] = {a.x, a.y, a.z, a.w, b.x, b.y, b.z, b.w};
    int c = 0;
#pragma unroll
    for (int j = 0; j < 8; ++j) {
      uint e = (w[j] >> 7) & 0xFFu;
      c += (e < 90u || e > 140u) ? 1 : 0;
    }
#pragma unroll
    for (int off = 32; off > 0; off >>= 1) c += __shfl_down(c, off);
    if (t == 0) s_flag = (c < 50) ? 1 : 0;   // 1 = bf16, 0 = fp32
  }
  __syncthreads();
  return s_flag;
}

// ---------------- K1: W2T | M | qsum partials | u (in-kernel handoff) -------
// 512 blocks, __launch_bounds__(256,2) -> 2 blocks/CU guaranteed -> ALL 512
// co-resident -> producer/consumer spin cannot deadlock.
// blocks [0,64):    W2T = (wv@wo)^T tiles
// blocks [64,128):  M = wk @ wq^T tiles          [producer: +1 on CTR[0]]
// blocks [128,384): qsum partials over queries   [producer: +1 on CTR[0]]
// blocks [384,512): u[b,t] = M[t,:].qsum[b,:]    [consumer: spin for 320]
// CTR[0], CTR[1] both harness-poisoned to the same bytes; delta = #increments.
__global__ __launch_bounds__(256, 2) void prep_u(
    const void* __restrict__ queries,
    const void* __restrict__ wq, const void* __restrict__ wk,
    const void* __restrict__ wv, const void* __restrict__ wo,
    float* __restrict__ P, ushort* __restrict__ W2T, float* __restrict__ M,
    float* __restrict__ U, uint* __restrict__ CTR) {
  __shared__ __align__(16) char smem[19456];
  ushort* As = (ushort*)smem;              // 5120 B
  ushort* Bs = (ushort*)(smem + 5120);     // 5120 B
  ushort* Ts = (ushort*)(smem + 10240);    // 9216 B
  int bf = detect_bf16(wq);
  int blk = blockIdx.x;
  int t = threadIdx.x;
  int w = t >> 6, lane = t & 63;
  int quad = lane >> 4, l16 = lane & 15;

  if (blk < 64) {
    // ---- W2T = (wv@wo)^T ---- (not needed by u; no increment)
    int n0 = (blk & 7) * 64, m0 = (blk >> 3) * 64;
    floatx4 acc[4] = {{0,0,0,0},{0,0,0,0},{0,0,0,0},{0,0,0,0}};
    int am = t >> 2, ak = (t & 3) * 8;
    int kp = t >> 4, nb = (t & 15) * 4;
    for (int k0 = 0; k0 < DMODEL; k0 += 32) {
      float a8[8];
      ld8v(wv, (size_t)(m0 + am) * DMODEL + k0 + ak, bf, a8);
      union { ushort s[8]; uint4 v; } ap;
#pragma unroll
      for (int j = 0; j < 8; ++j) ap.s[j] = f2b(a8[j]);
      *(uint4*)(&As[am * LDK + ak]) = ap.v;
      float b0[4], b1[4];
      ld4v(wo, (size_t)(k0 + 2 * kp) * DMODEL + n0 + nb, bf, b0);
      ld4v(wo, (size_t)(k0 + 2 * kp + 1) * DMODEL + n0 + nb, bf, b1);
#pragma unroll
      for (int i = 0; i < 4; ++i) {
        ushort2 pr; pr.x = f2b(b0[i]); pr.y = f2b(b1[i]);
        *(ushort2*)(&Bs[(nb + i) * LDK + 2 * kp]) = pr;
      }
      __syncthreads();
      short8 af = *(const short8*)(&As[(w * 16 + l16) * LDK + quad * 8]);
#pragma unroll
      for (int c = 0; c < 4; ++c) {
        short8 bfr = *(const short8*)(&Bs[(c * 16 + l16) * LDK + quad * 8]);
        acc[c] = __builtin_amdgcn_mfma_f32_16x16x32_bf16(af, bfr, acc[c], 0, 0, 0);
      }
      __syncthreads();
    }
#pragma unroll
    for (int c = 0; c < 4; ++c) {
      int cl = c * 16 + l16;
#pragma unroll
      for (int r = 0; r < 4; ++r)
        Ts[cl * 72 + (w * 16 + quad * 4 + r)] = f2b(acc[c][r]);
    }
    __syncthreads();
    int nl = t >> 2, ch = t & 3;
    uint4 v0 = *(const uint4*)(&Ts[nl * 72 + ch * 16]);
    uint4 v1 = *(const uint4*)(&Ts[nl * 72 + ch * 16 + 8]);
    ushort* dst = W2T + (size_t)(n0 + nl) * DMODEL + m0 + ch * 16;
    *(uint4*)dst = v0;
    *(uint4*)(dst + 8) = v1;
  } else if (blk < 128) {
    // ---- M[t,d] = sum_j wk[t,j]*wq[d,j] ----
    int wb = blk - 64;
    int m0 = (wb >> 3) * 64, n0 = (wb & 7) * 64;
    floatx4 acc[4] = {{0,0,0,0},{0,0,0,0},{0,0,0,0},{0,0,0,0}};
    int am = t >> 2, ak = (t & 3) * 8;
    for (int k0 = 0; k0 < DMODEL; k0 += 32) {
      float a8[8], b8[8];
      ld8v(wk, (size_t)(m0 + am) * DMODEL + k0 + ak, bf, a8);
      ld8v(wq, (size_t)(n0 + am) * DMODEL + k0 + ak, bf, b8);
      union { ushort s[8]; uint4 v; } ap, bp;
#pragma unroll
      for (int j = 0; j < 8; ++j) { ap.s[j] = f2b(a8[j]); bp.s[j] = f2b(b8[j]); }
      *(uint4*)(&As[am * LDK + ak]) = ap.v;
      *(uint4*)(&Bs[am * LDK + ak]) = bp.v;
      __syncthreads();
      short8 af = *(const short8*)(&As[(w * 16 + l16) * LDK + quad * 8]);
#pragma unroll
      for (int c = 0; c < 4; ++c) {
        short8 bfr = *(const short8*)(&Bs[(c * 16 + l16) * LDK + quad * 8]);
        acc[c] = __builtin_amdgcn_mfma_f32_16x16x32_bf16(af, bfr, acc[c], 0, 0, 0);
      }
      __syncthreads();
    }
    int mrow = m0 + w * 16 + quad * 4;
#pragma unroll
    for (int c = 0; c < 4; ++c) {
      int col = n0 + c * 16 + l16;
#pragma unroll
      for (int r = 0; r < 4; ++r)
        M[(size_t)(mrow + r) * DMODEL + col] = acc[c][r];
    }
    __syncthreads();                 // all waves' stores drained (vmcnt(0))
    if (t == 0) { __threadfence(); atomicAdd(&CTR[0], 1u); }
  } else if (blk < 384) {
    // ---- qsum partials ----
    int idx = blk - 128;
    int b = idx >> 6, c = idx & 63;
    size_t base = (((size_t)b * LEN + (size_t)c * 32) << 9) + t;
    float a0 = 0.f, a1 = 0.f;
#pragma unroll 8
    for (int l = 0; l < 32; ++l) {
      a0 += ld1(queries, base + ((size_t)l << 9), bf);
      a1 += ld1(queries, base + ((size_t)l << 9) + 256, bf);
    }
    P[(size_t)idx * DMODEL + t] = a0;
    P[(size_t)idx * DMODEL + t + 256] = a1;
    __syncthreads();
    if (t == 0) { __threadfence(); atomicAdd(&CTR[0], 1u); }
  } else {
    // ---- u[b,t] = M[t,:] . qsum[b,:]  (consumer) ----
    if (t == 0) {
      uint base = atomicAdd(&CTR[1], 0u);      // untouched poison sibling
      while (atomicAdd(&CTR[0], 0u) - base != 320u)
        __builtin_amdgcn_s_sleep(8);
    }
    __syncthreads();
    __threadfence();                            // acquire: invalidate stale
    float* qs = (float*)smem;
    int ib = blk - 384;
    int b = ib >> 5, g = ib & 31;
    for (int d = t; d < DMODEL; d += 256) {
      float a = 0.f;
#pragma unroll
      for (int c = 0; c < 64; ++c) a += P[(size_t)(b * 64 + c) * DMODEL + d];
      qs[d] = a;
    }
    __syncthreads();
    const float* q8 = qs + lane * 8;
#pragma unroll
    for (int i = 0; i < 4; ++i) {
      int tt = g * 16 + w * 4 + i;
      const float* mr = M + (size_t)tt * DMODEL + lane * 8;
      float4 m0 = *(const float4*)mr;
      float4 m1 = *(const float4*)(mr + 4);
      float acc = m0.x * q8[0] + m0.y * q8[1] + m0.z * q8[2] + m0.w * q8[3]
                + m1.x * q8[4] + m1.y * q8[5] + m1.z * q8[6] + m1.w * q8[7];
#pragma unroll
      for (int off = 32; off > 0; off >>= 1) acc += __shfl_down(acc, off);
      if (lane == 0) U[(size_t)b * DMODEL + tt] = acc;
    }
  }
}

// ---- K2 (fused, independent halves): VO = values @ W2T^T (blocks [0,256),
// XCD-swizzled, reg-prefetch, lgkm-only barriers) | mean_corr (blocks [256,768),
// 16 rows per block).
__global__ __launch_bounds__(256) void vo_mc(
    const void* __restrict__ values, const ushort* __restrict__ W2T,
    ushort* __restrict__ VO, const void* __restrict__ keys,
    const float* __restrict__ U, float* __restrict__ MC,
    const void* __restrict__ probe) {
  __shared__ __align__(16) char smem[20480];
  int bf = detect_bf16(probe);
  int blk = blockIdx.x, t = threadIdx.x;
  int w = t >> 6, lane = t & 63;

  if (blk < 256) {
    ushort* As = (ushort*)smem;
    ushort* Bs = (ushort*)(smem + 10240);
    int quad = lane >> 4, l16 = lane & 15;
    int n0 = (blk >> 6) * 128, m0 = (blk & 63) * 128;
    int wr = (w & 1) * 64, wc = (w >> 1) * 64;
    floatx4 acc[4][4];
#pragma unroll
    for (int r = 0; r < 4; ++r)
#pragma unroll
      for (int c = 0; c < 4; ++c) acc[r][c] = (floatx4){0, 0, 0, 0};
    int sr = t >> 2, sc = (t & 3) * 8;
    size_t a0i = (size_t)(m0 + sr) * DMODEL + sc;
    size_t a1i = (size_t)(m0 + sr + 64) * DMODEL + sc;
    const ushort* b0p = W2T + (size_t)(n0 + sr) * DMODEL + sc;
    const ushort* b1p = W2T + (size_t)(n0 + sr + 64) * DMODEL + sc;
    float ga0[8], ga1[8];
    uint4 gb0, gb1;
    ld8v(values, a0i, bf, ga0);
    ld8v(values, a1i, bf, ga1);
    gb0 = *(const uint4*)(b0p);
    gb1 = *(const uint4*)(b1p);
    for (int k0 = 0; k0 < DMODEL; k0 += 32) {
      union { ushort s[8]; uint4 v; } p0, p1;
#pragma unroll
      for (int j = 0; j < 8; ++j) { p0.s[j] = f2b(ga0[j]); p1.s[j] = f2b(ga1[j]); }
      *(uint4*)(&As[sr * LDK + sc])        = p0.v;
      *(uint4*)(&As[(sr + 64) * LDK + sc]) = p1.v;
      *(uint4*)(&Bs[sr * LDK + sc])        = gb0;
      *(uint4*)(&Bs[(sr + 64) * LDK + sc]) = gb1;
      int kn = k0 + 32;
      if (kn < DMODEL) {
        ld8v(values, a0i + kn, bf, ga0);
        ld8v(values, a1i + kn, bf, ga1);
        gb0 = *(const uint4*)(b0p + kn);
        gb1 = *(const uint4*)(b1p + kn);
      }
      block_sync_lds();
      short8 af[4], bfg[4];
#pragma unroll
      for (int r = 0; r < 4; ++r)
        af[r] = *(const short8*)(&As[(wr + r * 16 + l16) * LDK + quad * 8]);
#pragma unroll
      for (int c = 0; c < 4; ++c)
        bfg[c] = *(const short8*)(&Bs[(wc + c * 16 + l16) * LDK + quad * 8]);
#pragma unroll
      for (int r = 0; r < 4; ++r)
#pragma unroll
        for (int c = 0; c < 4; ++c)
          acc[r][c] = __builtin_amdgcn_mfma_f32_16x16x32_bf16(af[r], bfg[c], acc[r][c], 0, 0, 0);
      block_sync_lds();
    }
#pragma unroll
    for (int r = 0; r < 4; ++r) {
      int row = m0 + wr + r * 16 + quad * 4;
#pragma unroll
      for (int c = 0; c < 4; ++c) {
        int col = n0 + wc + c * 16 + l16;
#pragma unroll
        for (int rr = 0; rr < 4; ++rr)
          VO[(size_t)(row + rr) * DMODEL + col] = f2b(acc[r][c][rr]);
      }
    }
  } else {
    // ---- mean_corr: 512 blocks x 16 rows ----
    int ib = blk - 256;
#pragma unroll
    for (int p = 0; p < 4; ++p) {
      int wid = ib * 16 + w * 4 + p;
      int b = wid >> 11, j = wid & (LEN - 1);
      float kv[8];
      ld8v(keys, (((size_t)b * LEN + j) << 9) + lane * 8, bf, kv);
      const float* ub = U + (size_t)b * DMODEL + lane * 8;
      float acc = 0.f;
#pragma unroll
      for (int i = 0; i < 8; ++i) acc += kv[i] * ub[i];
#pragma unroll
      for (int off = 32; off > 0; off >>= 1) acc += __shfl_down(acc, off);
      if (lane == 0) MC[(size_t)b * LEN + j] = acc * (1.f / 16384.f);
    }
  }
}

// ------ K3: per-block redundant top-7+softmax, then gather-mix VO -> out ----
__global__ __launch_bounds__(256) void topk_mix_out(
    const float* __restrict__ MC, const ushort* __restrict__ VO,
    void* __restrict__ out, const void* __restrict__ probe) {
  __shared__ float vals[LEN];
  __shared__ float rv[4];
  __shared__ int ri[4];
  __shared__ float bw[TOPK];
  __shared__ int biA[TOPK];
  __shared__ float wsm[8];
  __shared__ int dsm[8];
  int bf = detect_bf16(probe);
  int blk = blockIdx.x, t = threadIdx.x;
  int w = t >> 6, lane = t & 63;
  int b = blk & 3, g = blk >> 2;
  for (int i = t; i < LEN; i += 256) vals[i] = MC[(size_t)b * LEN + i];
  __syncthreads();
  for (int it = 0; it < TOPK; ++it) {
    float bv = -3.0e38f; int bi = 0;
#pragma unroll
    for (int c = 0; c < LEN / 256; ++c) {
      int i = t + c * 256;
      float v = vals[i];
      if (v > bv) { bv = v; bi = i; }
    }
#pragma unroll
    for (int off = 32; off > 0; off >>= 1) {
      float ov = __shfl_down(bv, off);
      int   oi = __shfl_down(bi, off);
      if (ov > bv || (ov == bv && oi < bi)) { bv = ov; bi = oi; }
    }
    if (lane == 0) { rv[w] = bv; ri[w] = bi; }
    __syncthreads();
    if (t == 0) {
      float fv = rv[0]; int fi = ri[0];
      for (int x = 1; x < 4; ++x)
        if (rv[x] > fv || (rv[x] == fv && ri[x] < fi)) { fv = rv[x]; fi = ri[x]; }
      bw[it] = fv; biA[it] = fi;
      vals[fi] = -3.0e38f;
    }
    __syncthreads();
  }
  if (t == 0) {
    float m = bw[0];
    float e[TOPK], s = 0.f;
#pragma unroll
    for (int i = 0; i < TOPK; ++i) { e[i] = __expf(bw[i] - m); s += e[i]; }
    float inv = 1.f / s;
#pragma unroll
    for (int i = 0; i < TOPK; ++i) { wsm[i] = e[i] * inv; dsm[i] = biA[i]; }
  }
  __syncthreads();
  float w7[TOPK]; int dl7[TOPK];
#pragma unroll
  for (int i = 0; i < TOPK; ++i) { w7[i] = wsm[i]; dl7[i] = dsm[i]; }
  const ushort* VOb = VO + ((size_t)b * LEN << 9);
#pragma unroll
  for (int p = 0; p < 4; ++p) {
    int l = g * 16 + p * 4 + w;
    float acc[8] = {0,0,0,0,0,0,0,0};
#pragma unroll
    for (int i = 0; i < TOPK; ++i) {
      int src = (l + dl7[i]) & (LEN - 1);
      uint4 v = *(const uint4*)(VOb + ((size_t)src << 9) + lane * 8);
      const ushort* vs = (const ushort*)&v;
#pragma unroll
      for (int j = 0; j < 8; ++j) acc[j] += w7[i] * b2f(vs[j]);
    }
    size_t oidx = (((size_t)b * LEN + l) << 9) + lane * 8;
    if (bf) {
      union { ushort o[8]; uint4 v; } pk;
#pragma unroll
      for (int j = 0; j < 8; ++j) pk.o[j] = f2b(acc[j]);
      *(uint4*)((ushort*)out + oidx) = pk.v;
    } else {
      float4 f0 = {acc[0], acc[1], acc[2], acc[3]};
      float4 f1 = {acc[4], acc[5], acc[6], acc[7]};
      *(float4*)((float*)out + oidx) = f0;
      *(float4*)((float*)out + oidx + 4) = f1;
    }
  }
}

extern "C" void kernel_launch(void* const* d_in, const int* in_sizes, int n_in,
                              void* d_out, int out_size, void* d_ws, size_t ws_size,
                              hipStream_t stream) {
  const void* queries = d_in[0];
  const void* keys    = d_in[1];
  const void* values  = d_in[2];
  const void* wq      = d_in[3];
  const void* wk      = d_in[4];
  const void* wv      = d_in[5];
  const void* wo      = d_in[6];

  char* ws = (char*)d_ws;
  float*  P    = (float*)(ws + 0);           // 256*512*4 = 512 KB
  ushort* W2T  = (ushort*)(ws + 524288);     // 512*512*2 = 512 KB
  float*  M    = (float*)(ws + 1048576);     // 512*512*4 = 1 MB
  float*  U    = (float*)(ws + 2097152);     // 8 KB
  float*  MC   = (float*)(ws + 2105344);     // 32 KB -> ends 2138112
  uint*   CTR  = (uint*) (ws + 2142208);     // CTR[0] counter, CTR[1] baseline
  ushort* VO   = (ushort*)(ws + 4194304);    // 8192*512*2 = 8 MB; total ~12 MB

  prep_u<<<512, 256, 0, stream>>>(queries, wq, wk, wv, wo, P, W2T, M, U, CTR);
  vo_mc<<<768, 256, 0, stream>>>(values, W2T, VO, keys, U, MC, wq);
  topk_mix_out<<<512, 256, 0, stream>>>(MC, VO, d_out, wq);
}

// Round 14
// 142.568 us; speedup vs baseline: 1.2504x; 1.2504x over previous
//
#include <hip/hip_runtime.h>
#include <hip/hip_bf16.h>

#define DMODEL 512
#define LEN 2048
#define NBATCH 4
#define TOPK 7          // k = int(log(2048)) = 7
#define LDK 40          // padded LDS stride (bf16 elems): 80B rows keep 16B alignment

typedef __attribute__((ext_vector_type(8))) short short8;
typedef __attribute__((ext_vector_type(4))) float floatx4;

__device__ __forceinline__ float b2f(ushort h) {
  union { uint u; float f; } c; c.u = ((uint)h) << 16; return c.f;
}
__device__ __forceinline__ ushort f2b(float f) {
  union { float f; uint u; } c; c.f = f;
  uint u = c.u;
  uint r = (u + 0x7fffu + ((u >> 16) & 1u)) >> 16;   // RNE
  return (ushort)r;
}

__device__ __forceinline__ float ld1(const void* p, size_t i, int bf) {
  return bf ? b2f(((const ushort*)p)[i]) : ((const float*)p)[i];
}
__device__ __forceinline__ void ld4v(const void* p, size_t i, int bf, float* o) {
  if (bf) {
    uint2 v = *(const uint2*)((const ushort*)p + i);
    const ushort* s = (const ushort*)&v;
#pragma unroll
    for (int j = 0; j < 4; ++j) o[j] = b2f(s[j]);
  } else {
    float4 a = *(const float4*)((const float*)p + i);
    o[0] = a.x; o[1] = a.y; o[2] = a.z; o[3] = a.w;
  }
}
__device__ __forceinline__ void ld8v(const void* p, size_t i, int bf, float* o) {
  if (bf) {
    uint4 v = *(const uint4*)((const ushort*)p + i);
    const ushort* s = (const ushort*)&v;
#pragma unroll
    for (int j = 0; j < 8; ++j) o[j] = b2f(s[j]);
  } else {
    float4 a = *(const float4*)((const float*)p + i);
    float4 b = *(const float4*)((const float*)p + i + 4);
    o[0] = a.x; o[1] = a.y; o[2] = a.z; o[3] = a.w;
    o[4] = b.x; o[5] = b.y; o[6] = b.z; o[7] = b.w;
  }
}

// CK-style LDS barrier that does NOT drain vmcnt — keeps global loads in flight.
__device__ __forceinline__ void block_sync_lds() {
  asm volatile("s_waitcnt lgkmcnt(0)" ::: "memory");
  __builtin_amdgcn_s_barrier();
}

// per-block dtype self-detect from wq's first 512 words (L2-hot after first use).
__device__ __forceinline__ int detect_bf16(const void* probe) {
  __shared__ int s_flag;
  int t = threadIdx.x;
  if (t < 64) {
    const uint4* p = (const uint4*)probe;
    uint4 a = p[t * 2];
    uint4 b = p[t * 2 + 1];
    uint w[8] = {a.x, a.y, a.z, a.w, b.x, b.y, b.z, b.w};
    int c = 0;
#pragma unroll
    for (int j = 0; j < 8; ++j) {
      uint e = (w[j] >> 7) & 0xFFu;
      c += (e < 90u || e > 140u) ? 1 : 0;
    }
#pragma unroll
    for (int off = 32; off > 0; off >>= 1) c += __shfl_down(c, off);
    if (t == 0) s_flag = (c < 50) ? 1 : 0;   // 1 = bf16, 0 = fp32
  }
  __syncthreads();
  return s_flag;
}

// ---------------- K1 (fused, all input-independent work) --------------------
// blocks [0,64):    W2T = (wv@wo)^T tiles (bf16, transposed epilogue)
// blocks [64,128):  M = wk @ wq^T tiles (fp32 out)
// blocks [128,384): qsum partials over queries
// blocks [384,2432): values -> bf16 convert into VB
__global__ __launch_bounds__(256) void prep_k(
    const void* __restrict__ queries, const void* __restrict__ values,
    const void* __restrict__ wq, const void* __restrict__ wk,
    const void* __restrict__ wv, const void* __restrict__ wo,
    float* __restrict__ P, ushort* __restrict__ VB,
    ushort* __restrict__ W2T, float* __restrict__ M) {
  __shared__ ushort As[64 * LDK];
  __shared__ ushort Bs[64 * LDK];
  __shared__ ushort Ts[64 * 72];
  int bf = detect_bf16(wq);
  int blk = blockIdx.x;
  int t = threadIdx.x;
  int w = t >> 6, lane = t & 63;
  int quad = lane >> 4, l16 = lane & 15;

  if (blk < 64) {
    // ---- W2T = (wv@wo)^T ----
    int n0 = (blk & 7) * 64, m0 = (blk >> 3) * 64;
    floatx4 acc[4] = {{0,0,0,0},{0,0,0,0},{0,0,0,0},{0,0,0,0}};
    int am = t >> 2, ak = (t & 3) * 8;
    int kp = t >> 4, nb = (t & 15) * 4;
    for (int k0 = 0; k0 < DMODEL; k0 += 32) {
      float a8[8];
      ld8v(wv, (size_t)(m0 + am) * DMODEL + k0 + ak, bf, a8);
      union { ushort s[8]; uint4 v; } ap;
#pragma unroll
      for (int j = 0; j < 8; ++j) ap.s[j] = f2b(a8[j]);
      *(uint4*)(&As[am * LDK + ak]) = ap.v;
      float b0[4], b1[4];
      ld4v(wo, (size_t)(k0 + 2 * kp) * DMODEL + n0 + nb, bf, b0);
      ld4v(wo, (size_t)(k0 + 2 * kp + 1) * DMODEL + n0 + nb, bf, b1);
#pragma unroll
      for (int i = 0; i < 4; ++i) {
        ushort2 pr; pr.x = f2b(b0[i]); pr.y = f2b(b1[i]);
        *(ushort2*)(&Bs[(nb + i) * LDK + 2 * kp]) = pr;
      }
      __syncthreads();
      short8 af = *(const short8*)(&As[(w * 16 + l16) * LDK + quad * 8]);
#pragma unroll
      for (int c = 0; c < 4; ++c) {
        short8 bfr = *(const short8*)(&Bs[(c * 16 + l16) * LDK + quad * 8]);
        acc[c] = __builtin_amdgcn_mfma_f32_16x16x32_bf16(af, bfr, acc[c], 0, 0, 0);
      }
      __syncthreads();
    }
#pragma unroll
    for (int c = 0; c < 4; ++c) {
      int cl = c * 16 + l16;
#pragma unroll
      for (int r = 0; r < 4; ++r)
        Ts[cl * 72 + (w * 16 + quad * 4 + r)] = f2b(acc[c][r]);
    }
    __syncthreads();
    int nl = t >> 2, ch = t & 3;
    uint4 v0 = *(const uint4*)(&Ts[nl * 72 + ch * 16]);
    uint4 v1 = *(const uint4*)(&Ts[nl * 72 + ch * 16 + 8]);
    ushort* dst = W2T + (size_t)(n0 + nl) * DMODEL + m0 + ch * 16;
    *(uint4*)dst = v0;
    *(uint4*)(dst + 8) = v1;
  } else if (blk < 128) {
    // ---- M[t,d] = sum_j wk[t,j]*wq[d,j] ----
    int wb = blk - 64;
    int m0 = (wb >> 3) * 64, n0 = (wb & 7) * 64;
    floatx4 acc[4] = {{0,0,0,0},{0,0,0,0},{0,0,0,0},{0,0,0,0}};
    int am = t >> 2, ak = (t & 3) * 8;
    for (int k0 = 0; k0 < DMODEL; k0 += 32) {
      float a8[8], b8[8];
      ld8v(wk, (size_t)(m0 + am) * DMODEL + k0 + ak, bf, a8);
      ld8v(wq, (size_t)(n0 + am) * DMODEL + k0 + ak, bf, b8);
      union { ushort s[8]; uint4 v; } ap, bp;
#pragma unroll
      for (int j = 0; j < 8; ++j) { ap.s[j] = f2b(a8[j]); bp.s[j] = f2b(b8[j]); }
      *(uint4*)(&As[am * LDK + ak]) = ap.v;
      *(uint4*)(&Bs[am * LDK + ak]) = bp.v;
      __syncthreads();
      short8 af = *(const short8*)(&As[(w * 16 + l16) * LDK + quad * 8]);
#pragma unroll
      for (int c = 0; c < 4; ++c) {
        short8 bfr = *(const short8*)(&Bs[(c * 16 + l16) * LDK + quad * 8]);
        acc[c] = __builtin_amdgcn_mfma_f32_16x16x32_bf16(af, bfr, acc[c], 0, 0, 0);
      }
      __syncthreads();
    }
    int mrow = m0 + w * 16 + quad * 4;
#pragma unroll
    for (int c = 0; c < 4; ++c) {
      int col = n0 + c * 16 + l16;
#pragma unroll
      for (int r = 0; r < 4; ++r)
        M[(size_t)(mrow + r) * DMODEL + col] = acc[c][r];
    }
  } else if (blk < 384) {
    int idx = blk - 128;
    int b = idx >> 6, c = idx & 63;
    size_t base = (((size_t)b * LEN + (size_t)c * 32) << 9) + t;
    float a0 = 0.f, a1 = 0.f;
#pragma unroll 8
    for (int l = 0; l < 32; ++l) {
      a0 += ld1(queries, base + ((size_t)l << 9), bf);
      a1 += ld1(queries, base + ((size_t)l << 9) + 256, bf);
    }
    P[(size_t)idx * DMODEL + t] = a0;
    P[(size_t)idx * DMODEL + t + 256] = a1;
  } else {
    int r = (blk - 384) * 4 + w;
    float v[8];
    ld8v(values, ((size_t)r << 9) + lane * 8, bf, v);
    union { ushort o[8]; uint4 u; } pk;
#pragma unroll
    for (int j = 0; j < 8; ++j) pk.o[j] = f2b(v[j]);
    *(uint4*)(VB + ((size_t)r << 9) + lane * 8) = pk.u;
  }
}

// ---- K2 (fused): VO = VB @ W2T^T (blocks [0,256)) | u = M.qsum (blocks [256,384))
// GEMM: 128x128 tile, XCD-swizzled (n0 = blk>>6, m0 = blk&63), register
// prefetch across lgkm-only barriers.
__global__ __launch_bounds__(256) void gemm_u(
    const ushort* __restrict__ VB, const ushort* __restrict__ W2T,
    ushort* __restrict__ VO, const float* __restrict__ P,
    const float* __restrict__ M, float* __restrict__ U) {
  __shared__ __align__(16) char smem[20480];
  int blk = blockIdx.x, t = threadIdx.x;
  int w = t >> 6, lane = t & 63;

  if (blk < 256) {
    ushort* As = (ushort*)smem;
    ushort* Bs = (ushort*)(smem + 10240);
    int quad = lane >> 4, l16 = lane & 15;
    int n0 = (blk >> 6) * 128, m0 = (blk & 63) * 128;
    int wr = (w & 1) * 64, wc = (w >> 1) * 64;
    floatx4 acc[4][4];
#pragma unroll
    for (int r = 0; r < 4; ++r)
#pragma unroll
      for (int c = 0; c < 4; ++c) acc[r][c] = (floatx4){0, 0, 0, 0};
    int sr = t >> 2, sc = (t & 3) * 8;
    const ushort* a0p = VB + (size_t)(m0 + sr) * DMODEL + sc;
    const ushort* a1p = VB + (size_t)(m0 + sr + 64) * DMODEL + sc;
    const ushort* b0p = W2T + (size_t)(n0 + sr) * DMODEL + sc;
    const ushort* b1p = W2T + (size_t)(n0 + sr + 64) * DMODEL + sc;
    uint4 ga0 = *(const uint4*)(a0p), ga1 = *(const uint4*)(a1p);
    uint4 gb0 = *(const uint4*)(b0p), gb1 = *(const uint4*)(b1p);
    for (int k0 = 0; k0 < DMODEL; k0 += 32) {
      *(uint4*)(&As[sr * LDK + sc])        = ga0;
      *(uint4*)(&As[(sr + 64) * LDK + sc]) = ga1;
      *(uint4*)(&Bs[sr * LDK + sc])        = gb0;
      *(uint4*)(&Bs[(sr + 64) * LDK + sc]) = gb1;
      int kn = k0 + 32;
      if (kn < DMODEL) {
        ga0 = *(const uint4*)(a0p + kn); ga1 = *(const uint4*)(a1p + kn);
        gb0 = *(const uint4*)(b0p + kn); gb1 = *(const uint4*)(b1p + kn);
      }
      block_sync_lds();
      short8 af[4], bfg[4];
#pragma unroll
      for (int r = 0; r < 4; ++r)
        af[r] = *(const short8*)(&As[(wr + r * 16 + l16) * LDK + quad * 8]);
#pragma unroll
      for (int c = 0; c < 4; ++c)
        bfg[c] = *(const short8*)(&Bs[(wc + c * 16 + l16) * LDK + quad * 8]);
#pragma unroll
      for (int r = 0; r < 4; ++r)
#pragma unroll
        for (int c = 0; c < 4; ++c)
          acc[r][c] = __builtin_amdgcn_mfma_f32_16x16x32_bf16(af[r], bfg[c], acc[r][c], 0, 0, 0);
      block_sync_lds();
    }
#pragma unroll
    for (int r = 0; r < 4; ++r) {
      int row = m0 + wr + r * 16 + quad * 4;
#pragma unroll
      for (int c = 0; c < 4; ++c) {
        int col = n0 + wc + c * 16 + l16;
#pragma unroll
        for (int rr = 0; rr < 4; ++rr)
          VO[(size_t)(row + rr) * DMODEL + col] = f2b(acc[r][c][rr]);
      }
    }
  } else {
    // ---- u[b,t] = M[t,:] . qsum[b,:] ----
    float* qs = (float*)smem;
    int ib = blk - 256;
    int b = ib >> 5, g = ib & 31;
    for (int d = t; d < DMODEL; d += 256) {
      float a = 0.f;
#pragma unroll
      for (int c = 0; c < 64; ++c) a += P[(size_t)(b * 64 + c) * DMODEL + d];
      qs[d] = a;
    }
    __syncthreads();
    const float* q8 = qs + lane * 8;
#pragma unroll
    for (int i = 0; i < 4; ++i) {
      int tt = g * 16 + w * 4 + i;
      const float* mr = M + (size_t)tt * DMODEL + lane * 8;
      float4 m0 = *(const float4*)mr;
      float4 m1 = *(const float4*)(mr + 4);
      float acc = m0.x * q8[0] + m0.y * q8[1] + m0.z * q8[2] + m0.w * q8[3]
                + m1.x * q8[4] + m1.y * q8[5] + m1.z * q8[6] + m1.w * q8[7];
#pragma unroll
      for (int off = 32; off > 0; off >>= 1) acc += __shfl_down(acc, off);
      if (lane == 0) U[(size_t)b * DMODEL + tt] = acc;
    }
  }
}

// ---------------- K3: mean_corr[b,j] = (keys[b,j,:] . u[b,:]) / (H*L) -------
__global__ __launch_bounds__(256) void mean_corr_k(
    const void* __restrict__ keys, const float* __restrict__ u,
    float* __restrict__ mc, const void* __restrict__ probe) {
  int bf = detect_bf16(probe);
  int wid = (blockIdx.x * 256 + threadIdx.x) >> 6;
  int lane = threadIdx.x & 63;
  int b = wid >> 11, j = wid & (LEN - 1);
  float kv[8];
  ld8v(keys, (((size_t)b * LEN + j) << 9) + lane * 8, bf, kv);
  const float* ub = u + (size_t)b * DMODEL + lane * 8;
  float acc = 0.f;
#pragma unroll
  for (int i = 0; i < 8; ++i) acc += kv[i] * ub[i];
#pragma unroll
  for (int off = 32; off > 0; off >>= 1) acc += __shfl_down(acc, off);
  if (lane == 0) mc[(size_t)b * LEN + j] = acc * (1.f / 16384.f);
}

// ------ K4: per-block redundant top-7+softmax, then gather-mix VO -> out ----
// 512 blocks x 256 threads; phys blk = g*4 + b (batch b on XCDs {b, b+4} so
// VO[b] (4 MB) stays L2-resident). Block handles rows [g*16, g*16+16).
__global__ __launch_bounds__(256) void topk_mix_out(
    const float* __restrict__ MC, const ushort* __restrict__ VO,
    void* __restrict__ out, const void* __restrict__ probe) {
  __shared__ float vals[LEN];
  __shared__ float rv[4];
  __shared__ int ri[4];
  __shared__ float bw[TOPK];
  __shared__ int biA[TOPK];
  __shared__ float wsm[8];
  __shared__ int dsm[8];
  int bf = detect_bf16(probe);
  int blk = blockIdx.x, t = threadIdx.x;
  int w = t >> 6, lane = t & 63;
  int b = blk & 3, g = blk >> 2;
  for (int i = t; i < LEN; i += 256) vals[i] = MC[(size_t)b * LEN + i];
  __syncthreads();
  for (int it = 0; it < TOPK; ++it) {
    float bv = -3.0e38f; int bi = 0;
#pragma unroll
    for (int c = 0; c < LEN / 256; ++c) {
      int i = t + c * 256;
      float v = vals[i];
      if (v > bv) { bv = v; bi = i; }
    }
#pragma unroll
    for (int off = 32; off > 0; off >>= 1) {
      float ov = __shfl_down(bv, off);
      int   oi = __shfl_down(bi, off);
      if (ov > bv || (ov == bv && oi < bi)) { bv = ov; bi = oi; }
    }
    if (lane == 0) { rv[w] = bv; ri[w] = bi; }
    __syncthreads();
    if (t == 0) {
      float fv = rv[0]; int fi = ri[0];
      for (int x = 1; x < 4; ++x)
        if (rv[x] > fv || (rv[x] == fv && ri[x] < fi)) { fv = rv[x]; fi = ri[x]; }
      bw[it] = fv; biA[it] = fi;
      vals[fi] = -3.0e38f;
    }
    __syncthreads();
  }
  if (t == 0) {
    float m = bw[0];
    float e[TOPK], s = 0.f;
#pragma unroll
    for (int i = 0; i < TOPK; ++i) { e[i] = __expf(bw[i] - m); s += e[i]; }
    float inv = 1.f / s;
#pragma unroll
    for (int i = 0; i < TOPK; ++i) { wsm[i] = e[i] * inv; dsm[i] = biA[i]; }
  }
  __syncthreads();
  float w7[TOPK]; int dl7[TOPK];
#pragma unroll
  for (int i = 0; i < TOPK; ++i) { w7[i] = wsm[i]; dl7[i] = dsm[i]; }
  const ushort* VOb = VO + ((size_t)b * LEN << 9);
#pragma unroll
  for (int p = 0; p < 4; ++p) {
    int l = g * 16 + p * 4 + w;
    float acc[8] = {0,0,0,0,0,0,0,0};
#pragma unroll
    for (int i = 0; i < TOPK; ++i) {
      int src = (l + dl7[i]) & (LEN - 1);
      uint4 v = *(const uint4*)(VOb + ((size_t)src << 9) + lane * 8);
      const ushort* vs = (const ushort*)&v;
#pragma unroll
      for (int j = 0; j < 8; ++j) acc[j] += w7[i] * b2f(vs[j]);
    }
    size_t oidx = (((size_t)b * LEN + l) << 9) + lane * 8;
    if (bf) {
      union { ushort o[8]; uint4 v; } pk;
#pragma unroll
      for (int j = 0; j < 8; ++j) pk.o[j] = f2b(acc[j]);
      *(uint4*)((ushort*)out + oidx) = pk.v;
    } else {
      float4 f0 = {acc[0], acc[1], acc[2], acc[3]};
      float4 f1 = {acc[4], acc[5], acc[6], acc[7]};
      *(float4*)((float*)out + oidx) = f0;
      *(float4*)((float*)out + oidx + 4) = f1;
    }
  }
}

extern "C" void kernel_launch(void* const* d_in, const int* in_sizes, int n_in,
                              void* d_out, int out_size, void* d_ws, size_t ws_size,
                              hipStream_t stream) {
  const void* queries = d_in[0];
  const void* keys    = d_in[1];
  const void* values  = d_in[2];
  const void* wq      = d_in[3];
  const void* wk      = d_in[4];
  const void* wv      = d_in[5];
  const void* wo      = d_in[6];

  char* ws = (char*)d_ws;
  float*  P    = (float*)(ws + 0);           // 256*512*4 = 512 KB
  ushort* W2T  = (ushort*)(ws + 524288);     // 512*512*2 = 512 KB
  float*  M    = (float*)(ws + 1048576);     // 512*512*4 = 1 MB
  float*  U    = (float*)(ws + 2097152);     // 8 KB
  float*  MC   = (float*)(ws + 2105344);     // 32 KB
  ushort* VB   = (ushort*)(ws + 4194304);    // 8192*512*2 = 8 MB
  ushort* VO   = (ushort*)(ws + 12582912);   // 8192*512*2 = 8 MB; total ~20 MB

  prep_k<<<2432, 256, 0, stream>>>(queries, values, wq, wk, wv, wo, P, VB, W2T, M);
  gemm_u<<<384, 256, 0, stream>>>(VB, W2T, VO, P, M, U);
  mean_corr_k<<<NBATCH * LEN / 4, 256, 0, stream>>>(keys, U, MC, wq);
  topk_mix_out<<<512, 256, 0, stream>>>(MC, VO, d_out, wq);
}